// Round 17
// baseline (146.166 us; speedup 1.0000x reference)
//
#include <hip/hip_runtime.h>
#include <hip/hip_bf16.h>

#define NEXP 8
#define NEMB 1024
#define NTOK 8192
#define BK 64
#define NK  (NEMB / BK)   // 16 K-tiles
#define NIT (NK / 2)      // 8 pipeline iterations (main)
#define BLD_STRIPE 512

typedef __attribute__((ext_vector_type(8))) short  bf16x8;
typedef __attribute__((ext_vector_type(8))) unsigned short u16x8;
typedef __attribute__((ext_vector_type(4))) float  f32x4;

// ---- workspace layout (bytes) ----
#define XB_BYTES   (NTOK * NEMB * 2)
#define WB_BYTES   (NEXP * NEMB * NEMB * 2)
#define CNT_OFF    (XB_BYTES + WB_BYTES)
#define LTOK_OFF   (CNT_OFF + 256)
#define LWT_OFF    (LTOK_OFF + NEXP * NTOK * 4)
#define SELW_OFF   (LWT_OFF + NEXP * NTOK * 4)

__device__ __forceinline__ unsigned short f2bf(float f) {
    unsigned u = __builtin_bit_cast(unsigned, f);
    unsigned r = (u + 0x7fffu + ((u >> 16) & 1u)) >> 16;
    return (unsigned short)r;
}

// ---------------- fused: expert_w -> bf16 (blocks 0..4095) + gating (rest) ----------------
__global__ __launch_bounds__(256)
void k_prep(const float* __restrict__ x, const float* __restrict__ gw,
            const float* __restrict__ ew, unsigned short* __restrict__ wb,
            unsigned short* __restrict__ xb, int4* __restrict__ selw) {
    if (blockIdx.x < 4096) {
        int i = (blockIdx.x * 256 + threadIdx.x) * 8;
        f32x4 v0 = *reinterpret_cast<const f32x4*>(ew + i);
        f32x4 v1 = *reinterpret_cast<const f32x4*>(ew + i + 4);
        u16x8 o;
#pragma unroll
        for (int j = 0; j < 4; ++j) { o[j] = f2bf(v0[j]); o[4 + j] = f2bf(v1[j]); }
        *reinterpret_cast<u16x8*>(wb + i) = o;
        return;
    }
    int t = threadIdx.x, wave = t >> 6, lane = t & 63;
    int n = (blockIdx.x - 4096) * 4 + wave;

    const float* xr = x + (size_t)n * NEMB + lane * 16;
    f32x4 xv[4];
#pragma unroll
    for (int j = 0; j < 4; ++j) xv[j] = *reinterpret_cast<const f32x4*>(xr + j * 4);

    u16x8 o0, o1;
#pragma unroll
    for (int q = 0; q < 4; ++q) {
        o0[q] = f2bf(xv[0][q]); o0[4 + q] = f2bf(xv[1][q]);
        o1[q] = f2bf(xv[2][q]); o1[4 + q] = f2bf(xv[3][q]);
    }
    u16x8* xo = reinterpret_cast<u16x8*>(xb + (size_t)n * NEMB + lane * 16);
    xo[0] = o0; xo[1] = o1;

    float p[NEXP];
#pragma unroll
    for (int e = 0; e < NEXP; ++e) {
        const float* gr = gw + e * NEMB + lane * 16;
        f32x4 a = xv[0] * *reinterpret_cast<const f32x4*>(gr);
#pragma unroll
        for (int j = 1; j < 4; ++j) a += xv[j] * *reinterpret_cast<const f32x4*>(gr + j * 4);
        p[e] = a[0] + a[1] + a[2] + a[3];
    }
#pragma unroll
    for (int e = 0; e < NEXP; ++e) {
        float v = p[e];
#pragma unroll
        for (int m = 1; m < 64; m <<= 1) v += __shfl_xor(v, m, 64);
        p[e] = v;
    }
    if (lane == 0) {
        int e0 = 0; float b0 = p[0];
#pragma unroll
        for (int e = 1; e < NEXP; ++e) if (p[e] > b0) { b0 = p[e]; e0 = e; }
        int e1 = -1; float b1 = -3.4e38f;
#pragma unroll
        for (int e = 0; e < NEXP; ++e) if (e != e0 && p[e] > b1) { b1 = p[e]; e1 = e; }
        float ex = __expf(b1 - b0);
        float inv = 1.f / (1.f + ex);
        int4 s;
        s.x = e0; s.y = e1;
        s.z = __float_as_int(inv); s.w = __float_as_int(ex * inv);
        selw[n] = s;
    }
}

// ---------------- build combined per-expert token list (ltok pre-memset to -1) ------------
__global__ __launch_bounds__(256)
void k_build(const int4* __restrict__ selw, int* __restrict__ counts,
             int* __restrict__ ltok, float* __restrict__ lwt) {
    int e = blockIdx.y;
    int n0 = blockIdx.x * BLD_STRIPE;
    __shared__ int lcnt, base;
    __shared__ int   toks[BLD_STRIPE];
    __shared__ float wts[BLD_STRIPE];
    if (threadIdx.x == 0) lcnt = 0;
    __syncthreads();
    for (int i = threadIdx.x; i < BLD_STRIPE; i += 256) {
        int4 s = selw[n0 + i];
        if (s.x == e) {
            int p = atomicAdd(&lcnt, 1);
            toks[p] = n0 + i; wts[p] = __int_as_float(s.z);
        }
        if (s.y == e) {
            int p = atomicAdd(&lcnt, 1);
            toks[p] = n0 + i; wts[p] = __int_as_float(s.w);
        }
    }
    __syncthreads();
    if (threadIdx.x == 0) base = atomicAdd(&counts[e], lcnt);
    __syncthreads();
    for (int i = threadIdx.x; i < lcnt; i += 256) {
        ltok[e * NTOK + base + i] = toks[i];
        lwt[e * NTOK + base + i]  = wts[i];
    }
}

// ---------------- MAIN pass: R10 8-phase counted-vmcnt 256x256, full 256-row tiles -------
// Full tiles only (rb < counts[e]>>8): T = 4*Sum(floor) <= 256 w.h.p. -> all blocks
// co-resident (1/CU, 130 KB LDS), no serial makespan (R10's 2x pathology fixed).
// Grid 384 bids (e=bid&7): bids with rb >= floor exit; >256-bid actives need +6sigma.
// Schedule/swizzle/epilogue verbatim from R10 (refcheck'd absmax 0.0078).
__global__ __launch_bounds__(512, 2)
void k_gemm_main(const unsigned short* __restrict__ xb, const unsigned short* __restrict__ wb,
                 const int* __restrict__ counts, const int* __restrict__ ltok,
                 const float* __restrict__ lwt, float* __restrict__ out) {
    int e  = blockIdx.x & 7;          // XCD pin
    int bi = blockIdx.x >> 3;
    int rb = bi >> 2;
    int cb = bi & 3;
    if (rb >= (counts[e] >> 8)) return;   // full 256-row tiles only

    __shared__ unsigned short As[2][256 * BK];   // 2 x 32 KB
    __shared__ unsigned short Bs[2][256 * BK];   // 2 x 32 KB
    __shared__ int   tokS[256];
    __shared__ float wS[256];

    int t = threadIdx.x, lane = t & 63, wave = t >> 6;
    int wr = wave >> 2, wc = wave & 3;
    int fr = lane & 15, fq = lane >> 4, fs = fr & 7;
    int pk0 = fq ^ fs, pk1 = (fq + 4) ^ fs;

    if (t < 256) {
        tokS[t] = ltok[e * NTOK + rb * 256 + t];
        wS[t]   = lwt[e * NTOK + rb * 256 + t];
    }

    int c0 = t & 7, r0 = t >> 3;
    int csw = c0 ^ (r0 & 7);
    const unsigned short* aS[4];
    const unsigned short* bS[4];
#pragma unroll
    for (int j = 0; j < 4; ++j) {
        int row = j * 64 + r0;
        int tok = ltok[e * NTOK + rb * 256 + row];
        int tokc = tok < 0 ? 0 : tok;
        aS[j] = xb + (size_t)tokc * NEMB + csw * 8;
        bS[j] = wb + (size_t)e * NEMB * NEMB + (size_t)(cb * 256 + row) * NEMB + csw * 8;
    }
    int off0 = wave * 512;
    int off1 = 4096 + wave * 512;

#define GLL(src, dst)                                                                \
    __builtin_amdgcn_global_load_lds(                                                \
        (const __attribute__((address_space(1))) void*)(src),                        \
        (__attribute__((address_space(3))) void*)(dst), 16, 0, 0)
#define STG_A(buf, h, kt) if ((kt) < NK) {                                           \
    GLL(aS[(h)*2 + 0] + (kt)*BK, &As[buf][(h)*8192 + off0]);                         \
    GLL(aS[(h)*2 + 1] + (kt)*BK, &As[buf][(h)*8192 + off1]); }
#define STG_B(buf, h, kt) if ((kt) < NK) {                                           \
    GLL(bS[(h)*2 + 0] + (kt)*BK, &Bs[buf][(h)*8192 + off0]);                         \
    GLL(bS[(h)*2 + 1] + (kt)*BK, &Bs[buf][(h)*8192 + off1]); }

#define LDA(mh, buf) { _Pragma("unroll")                                             \
    for (int m = 0; m < 4; ++m) {                                                    \
        int row = ((mh)*4 + m)*32 + wr*16 + fr;                                      \
        af[m][0] = *reinterpret_cast<const bf16x8*>(&As[buf][row*BK + pk0*8]);       \
        af[m][1] = *reinterpret_cast<const bf16x8*>(&As[buf][row*BK + pk1*8]); } }
#define LDB(dst, nh, buf) { _Pragma("unroll")                                        \
    for (int n = 0; n < 2; ++n) {                                                    \
        int row = ((nh)*2 + n)*64 + wc*16 + fr;                                      \
        dst[n][0] = *reinterpret_cast<const bf16x8*>(&Bs[buf][row*BK + pk0*8]);      \
        dst[n][1] = *reinterpret_cast<const bf16x8*>(&Bs[buf][row*BK + pk1*8]); } }
#define MM(mh, nh, bfx) { _Pragma("unroll")                                          \
    for (int m = 0; m < 4; ++m) { _Pragma("unroll")                                  \
        for (int n = 0; n < 2; ++n) {                                                \
            acc[(mh)*4+m][(nh)*2+n] = __builtin_amdgcn_mfma_f32_16x16x32_bf16(       \
                af[m][0], bfx[n][0], acc[(mh)*4+m][(nh)*2+n], 0, 0, 0);              \
            acc[(mh)*4+m][(nh)*2+n] = __builtin_amdgcn_mfma_f32_16x16x32_bf16(       \
                af[m][1], bfx[n][1], acc[(mh)*4+m][(nh)*2+n], 0, 0, 0); } } }
#define BAR   __builtin_amdgcn_s_barrier()
#define LGKM0 asm volatile("s_waitcnt lgkmcnt(0)" ::: "memory")
#define VM6   asm volatile("s_waitcnt vmcnt(6)" ::: "memory")
#define VM0   asm volatile("s_waitcnt vmcnt(0)" ::: "memory")
#define PRI1  __builtin_amdgcn_s_setprio(1)
#define PRI0  __builtin_amdgcn_s_setprio(0)

    f32x4 acc[8][4];
#pragma unroll
    for (int m = 0; m < 8; ++m)
#pragma unroll
        for (int n = 0; n < 4; ++n) acc[m][n] = (f32x4){0.f, 0.f, 0.f, 0.f};

    bf16x8 af[4][2], bf0[2][2], bf1[2][2];

    // prologue: K0 full + K1 {Ah0,Bh0,Bh1}
    STG_A(0, 0, 0); STG_B(0, 0, 0); STG_A(0, 1, 0); STG_B(0, 1, 0);
    STG_A(1, 0, 1); STG_B(1, 0, 1); STG_B(1, 1, 1);
    VM6; LGKM0; BAR;

    for (int it = 0; it < NIT; ++it) {
        int kt1 = 2 * it + 1;
        int n0  = 2 * it + 2;
        int n1  = 2 * it + 3;
        bool lastIt = (it == NIT - 1);

        LDA(0, 0); LDB(bf0, 0, 0);
        STG_A(1, 1, kt1);
        BAR; LGKM0; PRI1; MM(0, 0, bf0); PRI0; BAR;

        LDB(bf1, 1, 0);
        STG_A(0, 0, n0);
        BAR; LGKM0; PRI1; MM(0, 1, bf1); PRI0; BAR;

        LDA(1, 0);
        STG_B(0, 0, n0);
        BAR; LGKM0; PRI1; MM(1, 0, bf0); PRI0; BAR;

        STG_A(0, 1, n0);
        if (lastIt) { VM0; } else { VM6; }
        BAR; PRI1; MM(1, 1, bf1); PRI0; BAR;

        LDA(0, 1); LDB(bf0, 0, 1);
        STG_B(0, 1, n0);
        BAR; LGKM0; PRI1; MM(0, 0, bf0); PRI0; BAR;

        LDB(bf1, 1, 1);
        STG_A(1, 0, n1);
        BAR; LGKM0; PRI1; MM(0, 1, bf1); PRI0; BAR;

        LDA(1, 1);
        STG_B(1, 0, n1);
        BAR; LGKM0; PRI1; MM(1, 0, bf0); PRI0; BAR;

        STG_B(1, 1, n1);
        if (!lastIt) { VM6; }
        BAR; PRI1; MM(1, 1, bf1); PRI0; BAR;
    }

#undef GLL
#undef STG_A
#undef STG_B
#undef LDA
#undef LDB
#undef MM
#undef BAR
#undef LGKM0
#undef VM6
#undef VM0
#undef PRI1
#undef PRI0

#pragma unroll
    for (int m = 0; m < 8; ++m) {
#pragma unroll
        for (int jj = 0; jj < 4; ++jj) {
            int row = m * 32 + wr * 16 + fq * 4 + jj;
            int tok = tokS[row];
            if (tok < 0) continue;
            float wgt = wS[row];
            float* orow = out + (size_t)tok * NEMB + cb * 256 + wc * 16 + fr;
#pragma unroll
            for (int n = 0; n < 4; ++n)
                unsafeAtomicAdd(orow + n * 64, wgt * acc[m][n][jj]);
        }
    }
}

// ---------------- REMAINDER pass: R15 128x128 drain kernel on leftover <256 rows ---------
// rb (128-row units) = 2*floor(counts/256) + slot, slot in {0,1}; covers rows
// [256*floor, counts) with -1 pad to next 128. Kernel body verbatim from R15.
__global__ __launch_bounds__(256)
void k_gemm_rem(const unsigned short* __restrict__ xb, const unsigned short* __restrict__ wb,
                const int* __restrict__ counts, const int* __restrict__ ltok,
                const float* __restrict__ lwt, float* __restrict__ out) {
    int e    = blockIdx.x & 7;        // XCD pin
    int j    = blockIdx.x >> 3;
    int cb   = j & 7;
    int slot = j >> 3;                // 0..1
    int cnt  = counts[e];
    int rb   = ((cnt >> 8) << 1) + slot;
    if (rb * 128 >= cnt) return;

    __shared__ unsigned short As[128 * BK];   // 16 KB
    __shared__ unsigned short Bs[128 * BK];   // 16 KB
    __shared__ int   tokS[128];
    __shared__ float wS[128];

    int t = threadIdx.x, lane = t & 63, wave = t >> 6;
    int wr = wave >> 1, wc = wave & 1;
    int fr = lane & 15, fq = lane >> 4, fs = fr & 7;

    if (t < 128) {
        tokS[t] = ltok[e * NTOK + rb * 128 + t];
        wS[t]   = lwt[e * NTOK + rb * 128 + t];
    }

    const unsigned short* aSrc[4];
    const unsigned short* bSrc[4];
    int ldsOff[4];
#pragma unroll
    for (int i = 0; i < 4; ++i) {
        int idx = i * 256 + t;
        int r   = idx >> 3;
        int csw = (idx & 7) ^ (r & 7);
        int tok = ltok[e * NTOK + rb * 128 + r];
        int tokc = tok < 0 ? 0 : tok;
        aSrc[i] = xb + (size_t)tokc * NEMB + csw * 8;
        bSrc[i] = wb + (size_t)e * NEMB * NEMB + (size_t)(cb * 128 + r) * NEMB + csw * 8;
        ldsOff[i] = (i * 256 + wave * 64) * 8;
    }

    f32x4 acc[4][4];
#pragma unroll
    for (int m = 0; m < 4; ++m)
#pragma unroll
        for (int n = 0; n < 4; ++n) acc[m][n] = (f32x4){0.f, 0.f, 0.f, 0.f};

    for (int kk = 0; kk < NK; ++kk) {
#pragma unroll
        for (int i = 0; i < 4; ++i) {
            __builtin_amdgcn_global_load_lds(
                (const __attribute__((address_space(1))) void*)(aSrc[i] + kk * BK),
                (__attribute__((address_space(3))) void*)(As + ldsOff[i]), 16, 0, 0);
            __builtin_amdgcn_global_load_lds(
                (const __attribute__((address_space(1))) void*)(bSrc[i] + kk * BK),
                (__attribute__((address_space(3))) void*)(Bs + ldsOff[i]), 16, 0, 0);
        }
        __syncthreads();

#pragma unroll
        for (int ks = 0; ks < 2; ++ks) {
            int ch = (fq + 4 * ks) ^ fs;
            bf16x8 af[4], bfr[4];
#pragma unroll
            for (int m = 0; m < 4; ++m)
                af[m] = *reinterpret_cast<const bf16x8*>(
                    As + (wr * 64 + m * 16 + fr) * BK + ch * 8);
#pragma unroll
            for (int n = 0; n < 4; ++n)
                bfr[n] = *reinterpret_cast<const bf16x8*>(
                    Bs + (wc * 64 + n * 16 + fr) * BK + ch * 8);
            __builtin_amdgcn_s_setprio(1);
#pragma unroll
            for (int m = 0; m < 4; ++m)
#pragma unroll
                for (int n = 0; n < 4; ++n)
                    acc[m][n] = __builtin_amdgcn_mfma_f32_16x16x32_bf16(
                        af[m], bfr[n], acc[m][n], 0, 0, 0);
            __builtin_amdgcn_s_setprio(0);
        }
        __syncthreads();
    }

#pragma unroll
    for (int m = 0; m < 4; ++m) {
#pragma unroll
        for (int jj = 0; jj < 4; ++jj) {
            int row = wr * 64 + m * 16 + fq * 4 + jj;
            int tok = tokS[row];
            if (tok < 0) continue;
            float wgt = wS[row];
            float* orow = out + (size_t)tok * NEMB + cb * 128 + wc * 64 + fr;
#pragma unroll
            for (int n = 0; n < 4; ++n)
                unsafeAtomicAdd(orow + n * 16, wgt * acc[m][n][jj]);
        }
    }
}

extern "C" void kernel_launch(void* const* d_in, const int* in_sizes, int n_in,
                              void* d_out, int out_size, void* d_ws, size_t ws_size,
                              hipStream_t stream) {
    const float* x  = (const float*)d_in[0];
    const float* gw = (const float*)d_in[1];
    const float* ew = (const float*)d_in[2];
    float* out = (float*)d_out;

    char* ws = (char*)d_ws;
    unsigned short* xb = (unsigned short*)(ws);
    unsigned short* wb = (unsigned short*)(ws + XB_BYTES);
    int*   counts = (int*)(ws + CNT_OFF);
    int*   ltok   = (int*)(ws + LTOK_OFF);
    float* lwt    = (float*)(ws + LWT_OFF);
    int4*  selw   = (int4*)(ws + SELW_OFF);

    hipMemsetAsync(counts, 0, 8 * sizeof(int), stream);
    hipMemsetAsync(ltok, 0xFF, NEXP * NTOK * sizeof(int), stream);   // -1 pad sentinel
    hipMemsetAsync(out, 0, (size_t)NTOK * NEMB * sizeof(float), stream);

    k_prep<<<4096 + NTOK / 4, 256, 0, stream>>>(x, gw, ew, wb, xb, selw);
    k_build<<<dim3(NTOK / BLD_STRIPE, NEXP), 256, 0, stream>>>(selw, counts, ltok, lwt);
    // main: full 256-row tiles, ~240-256 active blocks, 1/CU, no serialization
    k_gemm_main<<<384, 512, 0, stream>>>(xb, wb, counts, ltok, lwt, out);
    // remainder: leftover <256 rows per expert, 128^2 tiles
    k_gemm_rem<<<8 * 8 * 2, 256, 0, stream>>>(xb, wb, counts, ltok, lwt, out);
}

// Round 18
// 133.100 us; speedup vs baseline: 1.0982x; 1.0982x over previous
//
#include <hip/hip_runtime.h>
#include <hip/hip_bf16.h>

#define NEXP 8
#define NEMB 1024
#define NTOK 8192
#define BM 128
#define BN 128
#define BK 64
#define NK  (NEMB / BK)   // 16
#define RBS 24            // max row-tiles per expert slot
#define BLD_STRIPE 512

typedef __attribute__((ext_vector_type(8))) short  bf16x8;
typedef __attribute__((ext_vector_type(8))) unsigned short u16x8;
typedef __attribute__((ext_vector_type(4))) float  f32x4;

// ---- workspace layout (bytes) ----
#define XB_BYTES   (NTOK * NEMB * 2)
#define WB_BYTES   (NEXP * NEMB * NEMB * 2)
#define CNT_OFF    (XB_BYTES + WB_BYTES)
#define LTOK_OFF   (CNT_OFF + 256)
#define LWT_OFF    (LTOK_OFF + NEXP * NTOK * 4)
#define SELW_OFF   (LWT_OFF + NEXP * NTOK * 4)

__device__ __forceinline__ unsigned short f2bf(float f) {
    unsigned u = __builtin_bit_cast(unsigned, f);
    unsigned r = (u + 0x7fffu + ((u >> 16) & 1u)) >> 16;
    return (unsigned short)r;
}

// ---------------- fused: expert_w -> bf16 (blocks 0..4095) + gating (rest) ----------------
__global__ __launch_bounds__(256)
void k_prep(const float* __restrict__ x, const float* __restrict__ gw,
            const float* __restrict__ ew, unsigned short* __restrict__ wb,
            unsigned short* __restrict__ xb, int4* __restrict__ selw) {
    if (blockIdx.x < 4096) {
        int i = (blockIdx.x * 256 + threadIdx.x) * 8;
        f32x4 v0 = *reinterpret_cast<const f32x4*>(ew + i);
        f32x4 v1 = *reinterpret_cast<const f32x4*>(ew + i + 4);
        u16x8 o;
#pragma unroll
        for (int j = 0; j < 4; ++j) { o[j] = f2bf(v0[j]); o[4 + j] = f2bf(v1[j]); }
        *reinterpret_cast<u16x8*>(wb + i) = o;
        return;
    }
    int t = threadIdx.x, wave = t >> 6, lane = t & 63;
    int n = (blockIdx.x - 4096) * 4 + wave;

    const float* xr = x + (size_t)n * NEMB + lane * 16;
    f32x4 xv[4];
#pragma unroll
    for (int j = 0; j < 4; ++j) xv[j] = *reinterpret_cast<const f32x4*>(xr + j * 4);

    u16x8 o0, o1;
#pragma unroll
    for (int q = 0; q < 4; ++q) {
        o0[q] = f2bf(xv[0][q]); o0[4 + q] = f2bf(xv[1][q]);
        o1[q] = f2bf(xv[2][q]); o1[4 + q] = f2bf(xv[3][q]);
    }
    u16x8* xo = reinterpret_cast<u16x8*>(xb + (size_t)n * NEMB + lane * 16);
    xo[0] = o0; xo[1] = o1;

    float p[NEXP];
#pragma unroll
    for (int e = 0; e < NEXP; ++e) {
        const float* gr = gw + e * NEMB + lane * 16;
        f32x4 a = xv[0] * *reinterpret_cast<const f32x4*>(gr);
#pragma unroll
        for (int j = 1; j < 4; ++j) a += xv[j] * *reinterpret_cast<const f32x4*>(gr + j * 4);
        p[e] = a[0] + a[1] + a[2] + a[3];
    }
#pragma unroll
    for (int e = 0; e < NEXP; ++e) {
        float v = p[e];
#pragma unroll
        for (int m = 1; m < 64; m <<= 1) v += __shfl_xor(v, m, 64);
        p[e] = v;
    }
    if (lane == 0) {
        int e0 = 0; float b0 = p[0];
#pragma unroll
        for (int e = 1; e < NEXP; ++e) if (p[e] > b0) { b0 = p[e]; e0 = e; }
        int e1 = -1; float b1 = -3.4e38f;
#pragma unroll
        for (int e = 0; e < NEXP; ++e) if (e != e0 && p[e] > b1) { b1 = p[e]; e1 = e; }
        float ex = __expf(b1 - b0);
        float inv = 1.f / (1.f + ex);
        int4 s;
        s.x = e0; s.y = e1;
        s.z = __float_as_int(inv); s.w = __float_as_int(ex * inv);
        selw[n] = s;
    }
}

// ---------------- build combined per-expert token list ----------------
// ltok is pre-set to -1 (memset 0xFF); entries beyond counts[e] stay -1 (pad sentinel).
__global__ __launch_bounds__(256)
void k_build(const int4* __restrict__ selw, int* __restrict__ counts,
             int* __restrict__ ltok, float* __restrict__ lwt) {
    int e = blockIdx.y;
    int n0 = blockIdx.x * BLD_STRIPE;
    __shared__ int lcnt, base;
    __shared__ int   toks[BLD_STRIPE];
    __shared__ float wts[BLD_STRIPE];
    if (threadIdx.x == 0) lcnt = 0;
    __syncthreads();
    for (int i = threadIdx.x; i < BLD_STRIPE; i += 256) {
        int4 s = selw[n0 + i];
        if (s.x == e) {
            int p = atomicAdd(&lcnt, 1);
            toks[p] = n0 + i; wts[p] = __int_as_float(s.z);
        }
        if (s.y == e) {
            int p = atomicAdd(&lcnt, 1);
            toks[p] = n0 + i; wts[p] = __int_as_float(s.w);
        }
    }
    __syncthreads();
    if (threadIdx.x == 0) base = atomicAdd(&counts[e], lcnt);
    __syncthreads();
    for (int i = threadIdx.x; i < lcnt; i += 256) {
        ltok[e * NTOK + base + i] = toks[i];
        lwt[e * NTOK + base + i]  = wts[i];
    }
}

// ---------------- grouped gathered GEMM: measured-optimal config (R12/R15) ---------------
// 128x128 tile, BK=64, SINGLE-buffer LDS (33 KB) -> 4 blocks/CU = 16 waves/CU.
// Staging-wall model (closed over R9-R17): chip staging rate = 5.9 TB/s at this
// config = 94% of the 6.3 TB/s copy ceiling; GEMM time = staged bytes (528 MB)
// / rate = 89 us (observed 91). All alternatives measured worse: bigger tiles
// (fewer streams) collapse rate 1.5-3x; deeper pipelines are rate-bound too;
// fp8 staging fails the accuracy threshold. XCD pin e=bid&7 keeps the expert's
// 2 MB B panel L2-resident (FETCH 123->28 MB). Swizzle: LDS chunk (r,c) holds
// global chunk c^(r&7); read chunk (fq+4ks)^(fr&7) [0 bank conflicts]. Pad rows
// ltok=-1: gather clamped, epilogue skipped. Exactly 2 atomic adds/out element.
__global__ __launch_bounds__(256)
void k_gemm(const unsigned short* __restrict__ xb, const unsigned short* __restrict__ wb,
            const int* __restrict__ counts, const int* __restrict__ ltok,
            const float* __restrict__ lwt, float* __restrict__ out) {
    int b  = blockIdx.x;
    int e  = b & 7;               // XCD pin: consecutive ids round-robin XCDs
    int j  = b >> 3;
    int cb = j & 7;
    int rb = j >> 3;              // 0..RBS-1
    if (rb * BM >= counts[e]) return;

    __shared__ unsigned short As[BM * BK];   // 16 KB
    __shared__ unsigned short Bs[BN * BK];   // 16 KB
    __shared__ int   tokS[BM];
    __shared__ float wS[BM];

    int t = threadIdx.x, lane = t & 63, wave = t >> 6;
    int wr = wave >> 1, wc = wave & 1;
    int fr = lane & 15, fq = lane >> 4, fs = fr & 7;

    if (t < BM) {
        tokS[t] = ltok[e * NTOK + rb * BM + t];
        wS[t]   = lwt[e * NTOK + rb * BM + t];
    }

    const unsigned short* aSrc[4];
    const unsigned short* bSrc[4];
    int ldsOff[4];
#pragma unroll
    for (int i = 0; i < 4; ++i) {
        int idx = i * 256 + t;
        int r   = idx >> 3;
        int csw = (idx & 7) ^ (r & 7);
        int tok = ltok[e * NTOK + rb * BM + r];
        int tokc = tok < 0 ? 0 : tok;
        aSrc[i] = xb + (size_t)tokc * NEMB + csw * 8;
        bSrc[i] = wb + (size_t)e * NEMB * NEMB + (size_t)(cb * BN + r) * NEMB + csw * 8;
        ldsOff[i] = (i * 256 + wave * 64) * 8;   // wave-uniform base; HW adds lane*16B
    }

    f32x4 acc[4][4];
#pragma unroll
    for (int m = 0; m < 4; ++m)
#pragma unroll
        for (int n = 0; n < 4; ++n) acc[m][n] = (f32x4){0.f, 0.f, 0.f, 0.f};

    for (int kk = 0; kk < NK; ++kk) {
#pragma unroll
        for (int i = 0; i < 4; ++i) {
            __builtin_amdgcn_global_load_lds(
                (const __attribute__((address_space(1))) void*)(aSrc[i] + kk * BK),
                (__attribute__((address_space(3))) void*)(As + ldsOff[i]), 16, 0, 0);
            __builtin_amdgcn_global_load_lds(
                (const __attribute__((address_space(1))) void*)(bSrc[i] + kk * BK),
                (__attribute__((address_space(3))) void*)(Bs + ldsOff[i]), 16, 0, 0);
        }
        __syncthreads();    // drains vmcnt; staged tile visible to all waves

#pragma unroll
        for (int ks = 0; ks < 2; ++ks) {
            int ch = (fq + 4 * ks) ^ fs;
            bf16x8 af[4], bfr[4];
#pragma unroll
            for (int m = 0; m < 4; ++m)
                af[m] = *reinterpret_cast<const bf16x8*>(
                    As + (wr * 64 + m * 16 + fr) * BK + ch * 8);
#pragma unroll
            for (int n = 0; n < 4; ++n)
                bfr[n] = *reinterpret_cast<const bf16x8*>(
                    Bs + (wc * 64 + n * 16 + fr) * BK + ch * 8);
            __builtin_amdgcn_s_setprio(1);
#pragma unroll
            for (int m = 0; m < 4; ++m)
#pragma unroll
                for (int n = 0; n < 4; ++n)
                    acc[m][n] = __builtin_amdgcn_mfma_f32_16x16x32_bf16(
                        af[m], bfr[n], acc[m][n], 0, 0, 0);
            __builtin_amdgcn_s_setprio(0);
        }
        __syncthreads();    // all waves done reading before next stage overwrites
    }

    // epilogue: weighted atomic scatter (exactly 2 adds per out element)
#pragma unroll
    for (int m = 0; m < 4; ++m) {
#pragma unroll
        for (int jj = 0; jj < 4; ++jj) {
            int row = wr * 64 + m * 16 + fq * 4 + jj;
            int tok = tokS[row];
            if (tok < 0) continue;
            float wgt = wS[row];
            float* orow = out + (size_t)tok * NEMB + cb * BN + wc * 64 + fr;
#pragma unroll
            for (int n = 0; n < 4; ++n)
                unsafeAtomicAdd(orow + n * 16, wgt * acc[m][n][jj]);
        }
    }
}

extern "C" void kernel_launch(void* const* d_in, const int* in_sizes, int n_in,
                              void* d_out, int out_size, void* d_ws, size_t ws_size,
                              hipStream_t stream) {
    const float* x  = (const float*)d_in[0];
    const float* gw = (const float*)d_in[1];
    const float* ew = (const float*)d_in[2];
    float* out = (float*)d_out;

    char* ws = (char*)d_ws;
    unsigned short* xb = (unsigned short*)(ws);
    unsigned short* wb = (unsigned short*)(ws + XB_BYTES);
    int*   counts = (int*)(ws + CNT_OFF);
    int*   ltok   = (int*)(ws + LTOK_OFF);
    float* lwt    = (float*)(ws + LWT_OFF);
    int4*  selw   = (int4*)(ws + SELW_OFF);

    hipMemsetAsync(counts, 0, 8 * sizeof(int), stream);
    hipMemsetAsync(ltok, 0xFF, NEXP * NTOK * sizeof(int), stream);   // -1 pad sentinel
    hipMemsetAsync(out, 0, (size_t)NTOK * NEMB * sizeof(float), stream);

    // fused cvt + gate: 4096 cvt blocks + 2048 gate blocks (one launch)
    k_prep<<<4096 + NTOK / 4, 256, 0, stream>>>(x, gw, ew, wb, xb, selw);
    k_build<<<dim3(NTOK / BLD_STRIPE, NEXP), 256, 0, stream>>>(selw, counts, ltok, lwt);
    // flat grid, expert = bid&7 (XCD pin): 8 e x 8 cb x RBS rb = 1536 slots
    k_gemm<<<8 * 8 * RBS, 256, 0, stream>>>(xb, wb, counts, ltok, lwt, out);
}